// Round 5
// baseline (1113.014 us; speedup 1.0000x reference)
//
#include <hip/hip_runtime.h>
#include <hip/hip_fp16.h>
#include <math.h>

#define NF   128
#define HID  16
#define NPB  128          // nodes per bucket (dst >> 7)
#define CAP  768          // records per (xcd, bucket) cell; mean 511, +11 sigma
#define NXCD 8
#define OVF_CAP 262144    // statistically-unreachable overflow list

// ---------------------------------------------------------------------------
// zero cursor [NXCD*K] and ovf_cnt (ws is poisoned 0xAA before every call)
__global__ void zero_kernel(int* __restrict__ ptr, int n) {
    int i = blockIdx.x * blockDim.x + threadIdx.x;
    if (i < n) ptr[i] = 0;
}

// ---------------------------------------------------------------------------
// Bin edges into per-(XCD, bucket) cells with XCD-LOCAL (workgroup-scope)
// cursor atomics: these execute in the issuing XCD's own L2 (no sc1, no
// memory-side write-through). Each cell is touched by exactly one XCD
// (cell index includes XCC_ID), so L2-local atomicity is sufficient.
// Record = (dst & 127) << 17 | src   (src < 2^17, 7-bit local dst).
__global__ __launch_bounds__(256) void scatter_bin_kernel(
    const int* __restrict__ src, const int* __restrict__ dst,
    int* __restrict__ cursor, int* __restrict__ recs,
    int* __restrict__ ovf_cnt, int2* __restrict__ ovf, int E, int K)
{
    int e = blockIdx.x * blockDim.x + threadIdx.x;
    if (e >= E) return;
    int s = src[e], d = dst[e];

    int xcd;
    asm volatile("s_getreg_b32 %0, hwreg(HW_REG_XCC_ID)" : "=s"(xcd));
    xcd &= 7;

    int cell = xcd * K + (d >> 7);
    int pos = __hip_atomic_fetch_add(&cursor[cell], 1,
                                     __ATOMIC_RELAXED, __HIP_MEMORY_SCOPE_WORKGROUP);
    if (pos < CAP) {
        recs[(size_t)cell * CAP + pos] = ((d & 127) << 17) | s;
    } else {
        int op = atomicAdd(ovf_cnt, 1);          // device scope; ~never taken
        if (op < OVF_CAP) ovf[op] = make_int2(d, s);
    }
}

// ---------------------------------------------------------------------------
// p16 = x @ wl, q16 = x @ wr   (x: [N,128] f32, wl/wr: [128,16] f32, out fp16)
__global__ __launch_bounds__(256) void gemm1_kernel(
    const float* __restrict__ x, const float* __restrict__ wl,
    const float* __restrict__ wr, __half* __restrict__ p,
    __half* __restrict__ q, int N)
{
    __shared__ float swl[NF * HID];
    __shared__ float swr[NF * HID];
    __shared__ float xs[16][132];

    int tid  = threadIdx.x;
    int base = blockIdx.x * 16;

    for (int i = tid; i < NF * HID; i += 256) { swl[i] = wl[i]; swr[i] = wr[i]; }
    for (int i = tid; i < 16 * NF; i += 256) {
        int r = i >> 7, c = i & 127;
        int node = base + r;
        xs[r][c] = (node < N) ? x[(size_t)node * NF + c] : 0.f;
    }
    __syncthreads();

    int r = tid >> 4, f = tid & 15;
    int node = base + r;
    if (node >= N) return;

    float accl = 0.f, accr = 0.f;
    #pragma unroll
    for (int k = 0; k < NF; ++k) {
        float xv = xs[r][k];
        accl += xv * swl[k * HID + f];
        accr += xv * swr[k * HID + f];
    }
    p[(size_t)node * HID + f] = __float2half(accl);
    q[(size_t)node * HID + f] = __float2half(accr);
}

// ---------------------------------------------------------------------------
// p16 = h16 @ wl, q16 = h16 @ wr (16x16 fp32 weights; fp16 in/out, fp32 acc).
// q may alias h (tile staged in LDS before writes; blocks disjoint rows).
__global__ __launch_bounds__(256) void gemm2_kernel(
    const __half* __restrict__ h, const float* __restrict__ wl,
    const float* __restrict__ wr, __half* __restrict__ p,
    __half* __restrict__ q, int N)
{
    __shared__ float swl[HID * HID];
    __shared__ float swr[HID * HID];
    __shared__ float hs[256];

    int tid  = threadIdx.x;
    int base = blockIdx.x * 16;
    if (tid < HID * HID) { swl[tid] = wl[tid]; swr[tid] = wr[tid]; }
    int gi = base * HID + tid;
    hs[tid] = (gi < N * HID) ? __half2float(h[gi]) : 0.f;
    __syncthreads();

    int r = tid >> 4, f = tid & 15;
    int node = base + r;
    if (node >= N) return;

    float accl = 0.f, accr = 0.f;
    #pragma unroll
    for (int k = 0; k < HID; ++k) {
        float hv = hs[r * HID + k];
        accl += hv * swl[k * HID + f];
        accr += hv * swr[k * HID + f];
    }
    p[(size_t)node * HID + f] = __float2half(accl);
    q[(size_t)node * HID + f] = __float2half(accr);
}

// ---------------------------------------------------------------------------
// One block per bucket (128 nodes). fp32 accumulators in LDS (stride 17 to
// spread banks). Reads this bucket's 8 per-XCD cells contiguously; p16 rows
// are L2-resident gathers. Fused mean + bias + root + ReLU. h may alias q
// (each element read only by the thread that writes it).
__global__ __launch_bounds__(256) void bucket_agg_kernel(
    const int* __restrict__ cursor, const int* __restrict__ recs,
    const int* __restrict__ ovf_cnt, const int2* __restrict__ ovf,
    const __half* __restrict__ p, const __half* __restrict__ q,
    const float* __restrict__ b, __half* __restrict__ h, int N, int K)
{
    __shared__ float acc[NPB * 17];
    __shared__ int   deg[NPB];
    __shared__ int   s_ovf;

    int bkt  = blockIdx.x;
    int base = bkt << 7;
    int tid  = threadIdx.x;

    for (int i = tid; i < NPB * 17; i += 256) acc[i] = 0.f;
    if (tid < NPB) deg[tid] = 0;
    if (tid == 0) s_ovf = *ovf_cnt;
    __syncthreads();

    for (int xcd = 0; xcd < NXCD; ++xcd) {
        int cell = xcd * K + bkt;
        int len = cursor[cell]; if (len > CAP) len = CAP;
        const int* cr = recs + (size_t)cell * CAP;
        for (int r = tid; r < len; r += 256) {
            int rec = cr[r];
            int s  = rec & 0x1FFFF;
            int dl = rec >> 17;
            const __half2* pr = (const __half2*)(p + (size_t)s * HID);
            float* a = acc + dl * 17;
            #pragma unroll
            for (int j = 0; j < 8; ++j) {
                float2 v = __half22float2(pr[j]);
                atomicAdd(a + 2 * j,     v.x);
                atomicAdd(a + 2 * j + 1, v.y);
            }
            atomicAdd(&deg[dl], 1);
        }
    }

    if (s_ovf > 0) {                      // statistically never; correctness net
        int lim = s_ovf < OVF_CAP ? s_ovf : OVF_CAP;
        for (int r = tid; r < lim; r += 256) {
            int2 od = ovf[r];
            if ((od.x >> 7) != bkt) continue;
            int dl = od.x & 127;
            const __half2* pr = (const __half2*)(p + (size_t)od.y * HID);
            float* a = acc + dl * 17;
            #pragma unroll
            for (int j = 0; j < 8; ++j) {
                float2 v = __half22float2(pr[j]);
                atomicAdd(a + 2 * j,     v.x);
                atomicAdd(a + 2 * j + 1, v.y);
            }
            atomicAdd(&deg[dl], 1);
        }
    }
    __syncthreads();

    int nodes = N - base; if (nodes > NPB) nodes = NPB;
    for (int i = tid; i < nodes * HID; i += 256) {
        int dl = i >> 4, f = i & 15;
        int node = base + dl;
        float inv = 1.f / fmaxf((float)deg[dl], 1.f);
        float v = acc[dl * 17 + f] * inv + b[f]
                + __half2float(q[(size_t)node * HID + f]);
        h[(size_t)node * HID + f] = __float2half(fmaxf(v, 0.f));
    }
}

// ---------------------------------------------------------------------------
// per-edge: concat(h[src],h[dst]) -> fc1+relu -> fc2 -> log_softmax
__global__ __launch_bounds__(256) void edge_mlp_kernel(
    const int* __restrict__ src, const int* __restrict__ dst,
    const __half* __restrict__ h,
    const float* __restrict__ fc1w, const float* __restrict__ fc1b,
    const float* __restrict__ fc2w, const float* __restrict__ fc2b,
    float* __restrict__ out, int E)
{
    __shared__ float w1[32 * 16];
    __shared__ float b1[16];
    __shared__ float w2[32];
    __shared__ float b2[2];

    int tid = threadIdx.x;
    for (int i = tid; i < 512; i += 256) w1[i] = fc1w[i];
    if (tid < 16) b1[tid] = fc1b[tid];
    if (tid < 32) w2[tid] = fc2w[tid];
    if (tid < 2)  b2[tid] = fc2b[tid];
    __syncthreads();

    int e = blockIdx.x * blockDim.x + tid;
    if (e >= E) return;
    int s = src[e], d = dst[e];

    float feat[32];
    const __half2* hs2 = (const __half2*)(h + (size_t)s * HID);
    const __half2* hd2 = (const __half2*)(h + (size_t)d * HID);
    #pragma unroll
    for (int i = 0; i < 8; ++i) {
        float2 v = __half22float2(hs2[i]);
        feat[2*i+0] = v.x; feat[2*i+1] = v.y;
    }
    #pragma unroll
    for (int i = 0; i < 8; ++i) {
        float2 v = __half22float2(hd2[i]);
        feat[16+2*i+0] = v.x; feat[16+2*i+1] = v.y;
    }

    float z[16];
    #pragma unroll
    for (int j = 0; j < 16; ++j) z[j] = b1[j];
    #pragma unroll
    for (int i = 0; i < 32; ++i) {
        float fv = feat[i];
        #pragma unroll
        for (int j = 0; j < 16; ++j) z[j] += fv * w1[i * 16 + j];
    }

    float o0 = b2[0], o1 = b2[1];
    #pragma unroll
    for (int j = 0; j < 16; ++j) {
        float zj = fmaxf(z[j], 0.f);
        o0 += zj * w2[2 * j + 0];
        o1 += zj * w2[2 * j + 1];
    }

    float m = fmaxf(o0, o1);
    float lse = m + logf(expf(o0 - m) + expf(o1 - m));
    float2 res; res.x = o0 - lse; res.y = o1 - lse;
    ((float2*)out)[e] = res;
}

// ---------------------------------------------------------------------------
extern "C" void kernel_launch(void* const* d_in, const int* in_sizes, int n_in,
                              void* d_out, int out_size, void* d_ws, size_t ws_size,
                              hipStream_t stream)
{
    const float* x    = (const float*)d_in[0];
    const int*   ei   = (const int*)  d_in[1];
    const float* w1l  = (const float*)d_in[2];
    const float* b1l  = (const float*)d_in[3];
    const float* w1r  = (const float*)d_in[4];
    const float* w2l  = (const float*)d_in[5];
    const float* b2l  = (const float*)d_in[6];
    const float* w2r  = (const float*)d_in[7];
    const float* fc1w = (const float*)d_in[8];
    const float* fc1b = (const float*)d_in[9];
    const float* fc2w = (const float*)d_in[10];
    const float* fc2b = (const float*)d_in[11];
    float* out = (float*)d_out;

    int N = in_sizes[0] / NF;
    int E = in_sizes[1] / 2;
    const int* src = ei;
    const int* dst = ei + E;

    int K = (N + NPB - 1) / NPB;   // 782 buckets

    // ws layout: A16[N*16] h | B16[N*16] h | recs[8*K*CAP] i32 |
    //            cursor[8*K] i32 | ovf_cnt i32 | pad | ovf[OVF_CAP] int2
    // total ~26.7 MB
    __half* A16    = (__half*)d_ws;
    __half* B16    = A16 + (size_t)N * HID;
    int*    recs   = (int*)(B16 + (size_t)N * HID);
    int*    cursor = recs + (size_t)NXCD * K * CAP;
    int*    ovfcnt = cursor + (size_t)NXCD * K;
    int2*   ovf    = (int2*)(ovfcnt + 2);     // keep 8B alignment

    int ncur = NXCD * K + 1;                  // cursor + ovf_cnt (contiguous)

    // ---- build binned edge structure (once, reused by both layers) ----
    zero_kernel<<<(ncur + 255) / 256, 256, 0, stream>>>(cursor, ncur);
    scatter_bin_kernel<<<(E + 255) / 256, 256, 0, stream>>>(src, dst, cursor, recs,
                                                            ovfcnt, ovf, E, K);

    // ---- layer 1: p->A16, q->B16; aggregate writes h1 into B16 ----
    gemm1_kernel<<<(N + 15) / 16, 256, 0, stream>>>(x, w1l, w1r, A16, B16, N);
    bucket_agg_kernel<<<K, 256, 0, stream>>>(cursor, recs, ovfcnt, ovf,
                                             A16, B16, b1l, B16, N, K);

    // ---- layer 2: reads B16, p->A16, q->B16 (in-place); h2 into B16 ----
    gemm2_kernel<<<(N + 15) / 16, 256, 0, stream>>>(B16, w2l, w2r, A16, B16, N);
    bucket_agg_kernel<<<K, 256, 0, stream>>>(cursor, recs, ovfcnt, ovf,
                                             A16, B16, b2l, B16, N, K);

    // ---- edge MLP + log_softmax ----
    edge_mlp_kernel<<<(E + 255) / 256, 256, 0, stream>>>(src, dst, B16, fc1w, fc1b,
                                                         fc2w, fc2b, out, E);
}

// Round 6
// 501.011 us; speedup vs baseline: 2.2215x; 2.2215x over previous
//
#include <hip/hip_runtime.h>
#include <hip/hip_fp16.h>
#include <math.h>

#define NF   128
#define HID  16
#define NPB  128          // nodes per bucket (dst >> 7)
#define CAP  768          // records per (xcd, bucket) cell; mean 511
#define NXCD 8
#define SMAX (NXCD * CAP) // max records per bucket in LDS sort (6144)
#define OVF_CAP 262144    // statistically-unreachable overflow list

// ---------------------------------------------------------------------------
__global__ void zero_kernel(int* __restrict__ ptr, int n) {
    int i = blockIdx.x * blockDim.x + threadIdx.x;
    if (i < n) ptr[i] = 0;
}

// ---------------------------------------------------------------------------
// Bin edges into per-(XCD, bucket) cells. Cursor atomics are workgroup-scope:
// they execute as RMW in the issuing XCD's own L2 (no memory-side
// write-through). Each cell is owned by exactly one XCD (index includes
// XCC_ID); empirically validated (R5 passed with absmax 0.031).
// Record = (dst & 127) << 17 | src   (src < 2^17).
__global__ __launch_bounds__(256) void scatter_bin_kernel(
    const int* __restrict__ src, const int* __restrict__ dst,
    int* __restrict__ cursor, int* __restrict__ recs,
    int* __restrict__ ovf_cnt, int2* __restrict__ ovf, int E, int K)
{
    int e = blockIdx.x * blockDim.x + threadIdx.x;
    if (e >= E) return;
    int s = src[e], d = dst[e];

    int xcd;
    asm volatile("s_getreg_b32 %0, hwreg(HW_REG_XCC_ID)" : "=s"(xcd));
    xcd &= 7;

    int cell = xcd * K + (d >> 7);
    int pos = __hip_atomic_fetch_add(&cursor[cell], 1,
                                     __ATOMIC_RELAXED, __HIP_MEMORY_SCOPE_WORKGROUP);
    if (pos < CAP) {
        recs[(size_t)cell * CAP + pos] = ((d & 127) << 17) | s;
    } else {
        int op = atomicAdd(ovf_cnt, 1);          // device scope; ~never taken
        if (op < OVF_CAP) ovf[op] = make_int2(d, s);
    }
}

// ---------------------------------------------------------------------------
// p16 = x @ wl, q16 = x @ wr
__global__ __launch_bounds__(256) void gemm1_kernel(
    const float* __restrict__ x, const float* __restrict__ wl,
    const float* __restrict__ wr, __half* __restrict__ p,
    __half* __restrict__ q, int N)
{
    __shared__ float swl[NF * HID];
    __shared__ float swr[NF * HID];
    __shared__ float xs[16][132];

    int tid  = threadIdx.x;
    int base = blockIdx.x * 16;

    for (int i = tid; i < NF * HID; i += 256) { swl[i] = wl[i]; swr[i] = wr[i]; }
    for (int i = tid; i < 16 * NF; i += 256) {
        int r = i >> 7, c = i & 127;
        int node = base + r;
        xs[r][c] = (node < N) ? x[(size_t)node * NF + c] : 0.f;
    }
    __syncthreads();

    int r = tid >> 4, f = tid & 15;
    int node = base + r;
    if (node >= N) return;

    float accl = 0.f, accr = 0.f;
    #pragma unroll
    for (int k = 0; k < NF; ++k) {
        float xv = xs[r][k];
        accl += xv * swl[k * HID + f];
        accr += xv * swr[k * HID + f];
    }
    p[(size_t)node * HID + f] = __float2half(accl);
    q[(size_t)node * HID + f] = __float2half(accr);
}

// ---------------------------------------------------------------------------
// p16 = h16 @ wl, q16 = h16 @ wr; q may alias h (LDS-staged before writes)
__global__ __launch_bounds__(256) void gemm2_kernel(
    const __half* __restrict__ h, const float* __restrict__ wl,
    const float* __restrict__ wr, __half* __restrict__ p,
    __half* __restrict__ q, int N)
{
    __shared__ float swl[HID * HID];
    __shared__ float swr[HID * HID];
    __shared__ float hs[256];

    int tid  = threadIdx.x;
    int base = blockIdx.x * 16;
    if (tid < HID * HID) { swl[tid] = wl[tid]; swr[tid] = wr[tid]; }
    int gi = base * HID + tid;
    hs[tid] = (gi < N * HID) ? __half2float(h[gi]) : 0.f;
    __syncthreads();

    int r = tid >> 4, f = tid & 15;
    int node = base + r;
    if (node >= N) return;

    float accl = 0.f, accr = 0.f;
    #pragma unroll
    for (int k = 0; k < HID; ++k) {
        float hv = hs[r * HID + k];
        accl += hv * swl[k * HID + f];
        accr += hv * swr[k * HID + f];
    }
    p[(size_t)node * HID + f] = __float2half(accl);
    q[(size_t)node * HID + f] = __float2half(accr);
}

// ---------------------------------------------------------------------------
// One block per bucket (128 nodes). In-LDS counting sort of the bucket's
// records by local dst, then atomic-free register accumulation:
// 2 threads/node x 8 features, one 16B vector load per record.
// h may alias q (each element read only by its writer thread).
__global__ __launch_bounds__(256) void bucket_agg_kernel(
    const int* __restrict__ cursor, const int* __restrict__ recs,
    const int* __restrict__ ovf_cnt, const int2* __restrict__ ovf,
    const __half* __restrict__ p, const __half* __restrict__ q,
    const float* __restrict__ b, __half* __restrict__ h, int N, int K)
{
    __shared__ int sorted[SMAX];     // 24 KB: src ids grouped by local dst
    __shared__ int cnt[NPB];
    __shared__ int off[NPB];
    __shared__ int cur[NPB];
    __shared__ int scan[NPB];
    __shared__ int s_ovf;

    int bkt = blockIdx.x;
    int tid = threadIdx.x;

    if (tid < NPB) cnt[tid] = 0;
    if (tid == 0) { int v = *ovf_cnt; s_ovf = v < OVF_CAP ? v : OVF_CAP; }
    __syncthreads();

    // Phase A: count per local dst (1 LDS atomic / record)
    for (int xcd = 0; xcd < NXCD; ++xcd) {
        int cell = xcd * K + bkt;
        int len = cursor[cell]; if (len > CAP) len = CAP;
        const int* cr = recs + (size_t)cell * CAP;
        for (int r = tid; r < len; r += 256)
            atomicAdd(&cnt[((unsigned)cr[r]) >> 17], 1);
    }
    if (s_ovf > 0) {
        for (int r = tid; r < s_ovf; r += 256) {
            int2 od = ovf[r];
            if ((od.x >> 7) == bkt) atomicAdd(&cnt[od.x & 127], 1);
        }
    }
    __syncthreads();

    // Phase B: exclusive scan of cnt[128]
    if (tid < NPB) scan[tid] = cnt[tid];
    __syncthreads();
    for (int o = 1; o < NPB; o <<= 1) {
        int v = 0;
        if (tid < NPB && tid >= o) v = scan[tid - o];
        __syncthreads();
        if (tid < NPB) scan[tid] += v;
        __syncthreads();
    }
    if (tid < NPB) { int e = scan[tid] - cnt[tid]; off[tid] = e; cur[tid] = e; }
    __syncthreads();

    // Phase C: scatter src into dl-grouped slots (1 LDS atomic + 1 write)
    for (int xcd = 0; xcd < NXCD; ++xcd) {
        int cell = xcd * K + bkt;
        int len = cursor[cell]; if (len > CAP) len = CAP;
        const int* cr = recs + (size_t)cell * CAP;
        for (int r = tid; r < len; r += 256) {
            int rec = cr[r];
            int slot = atomicAdd(&cur[((unsigned)rec) >> 17], 1);
            if (slot < SMAX) sorted[slot] = rec & 0x1FFFF;
        }
    }
    if (s_ovf > 0) {
        for (int r = tid; r < s_ovf; r += 256) {
            int2 od = ovf[r];
            if ((od.x >> 7) == bkt) {
                int slot = atomicAdd(&cur[od.x & 127], 1);
                if (slot < SMAX) sorted[slot] = od.y;
            }
        }
    }
    __syncthreads();

    // Phase D: atomic-free accumulate. thread = (dl, half of features)
    int dl   = tid >> 1;
    int half = tid & 1;
    int node = (bkt << 7) + dl;
    if (node >= N) return;

    int st = off[dl];
    int n  = cnt[dl];
    if (st > SMAX) st = SMAX;
    if (st + n > SMAX) n = SMAX - st;

    float a0 = 0.f, a1 = 0.f, a2 = 0.f, a3 = 0.f,
          a4 = 0.f, a5 = 0.f, a6 = 0.f, a7 = 0.f;
    for (int i = 0; i < n; ++i) {
        int s = sorted[st + i];
        float4 raw = *(const float4*)(p + (size_t)s * HID + half * 8);
        float2 v0 = __half22float2(*(const __half2*)&raw.x);
        float2 v1 = __half22float2(*(const __half2*)&raw.y);
        float2 v2 = __half22float2(*(const __half2*)&raw.z);
        float2 v3 = __half22float2(*(const __half2*)&raw.w);
        a0 += v0.x; a1 += v0.y; a2 += v1.x; a3 += v1.y;
        a4 += v2.x; a5 += v2.y; a6 += v3.x; a7 += v3.y;
    }

    float inv = 1.f / fmaxf((float)cnt[dl], 1.f);
    int fb = half * 8;
    float4 qraw = *(const float4*)(q + (size_t)node * HID + fb);
    float2 q0 = __half22float2(*(const __half2*)&qraw.x);
    float2 q1 = __half22float2(*(const __half2*)&qraw.y);
    float2 q2 = __half22float2(*(const __half2*)&qraw.z);
    float2 q3 = __half22float2(*(const __half2*)&qraw.w);

    __half2 r0 = __floats2half2_rn(fmaxf(a0*inv + b[fb+0] + q0.x, 0.f),
                                   fmaxf(a1*inv + b[fb+1] + q0.y, 0.f));
    __half2 r1 = __floats2half2_rn(fmaxf(a2*inv + b[fb+2] + q1.x, 0.f),
                                   fmaxf(a3*inv + b[fb+3] + q1.y, 0.f));
    __half2 r2 = __floats2half2_rn(fmaxf(a4*inv + b[fb+4] + q2.x, 0.f),
                                   fmaxf(a5*inv + b[fb+5] + q2.y, 0.f));
    __half2 r3 = __floats2half2_rn(fmaxf(a6*inv + b[fb+6] + q3.x, 0.f),
                                   fmaxf(a7*inv + b[fb+7] + q3.y, 0.f));
    float4 res;
    *(__half2*)&res.x = r0; *(__half2*)&res.y = r1;
    *(__half2*)&res.z = r2; *(__half2*)&res.w = r3;
    *(float4*)(h + (size_t)node * HID + fb) = res;
}

// ---------------------------------------------------------------------------
// per-edge: concat(h[src],h[dst]) -> fc1+relu -> fc2 -> log_softmax
__global__ __launch_bounds__(256) void edge_mlp_kernel(
    const int* __restrict__ src, const int* __restrict__ dst,
    const __half* __restrict__ h,
    const float* __restrict__ fc1w, const float* __restrict__ fc1b,
    const float* __restrict__ fc2w, const float* __restrict__ fc2b,
    float* __restrict__ out, int E)
{
    __shared__ float w1[32 * 16];
    __shared__ float b1[16];
    __shared__ float w2[32];
    __shared__ float b2[2];

    int tid = threadIdx.x;
    for (int i = tid; i < 512; i += 256) w1[i] = fc1w[i];
    if (tid < 16) b1[tid] = fc1b[tid];
    if (tid < 32) w2[tid] = fc2w[tid];
    if (tid < 2)  b2[tid] = fc2b[tid];
    __syncthreads();

    int e = blockIdx.x * blockDim.x + tid;
    if (e >= E) return;
    int s = src[e], d = dst[e];

    float feat[32];
    const __half2* hs2 = (const __half2*)(h + (size_t)s * HID);
    const __half2* hd2 = (const __half2*)(h + (size_t)d * HID);
    #pragma unroll
    for (int i = 0; i < 8; ++i) {
        float2 v = __half22float2(hs2[i]);
        feat[2*i+0] = v.x; feat[2*i+1] = v.y;
    }
    #pragma unroll
    for (int i = 0; i < 8; ++i) {
        float2 v = __half22float2(hd2[i]);
        feat[16+2*i+0] = v.x; feat[16+2*i+1] = v.y;
    }

    float z[16];
    #pragma unroll
    for (int j = 0; j < 16; ++j) z[j] = b1[j];
    #pragma unroll
    for (int i = 0; i < 32; ++i) {
        float fv = feat[i];
        #pragma unroll
        for (int j = 0; j < 16; ++j) z[j] += fv * w1[i * 16 + j];
    }

    float o0 = b2[0], o1 = b2[1];
    #pragma unroll
    for (int j = 0; j < 16; ++j) {
        float zj = fmaxf(z[j], 0.f);
        o0 += zj * w2[2 * j + 0];
        o1 += zj * w2[2 * j + 1];
    }

    float m = fmaxf(o0, o1);
    float lse = m + logf(expf(o0 - m) + expf(o1 - m));
    float2 res; res.x = o0 - lse; res.y = o1 - lse;
    ((float2*)out)[e] = res;
}

// ---------------------------------------------------------------------------
extern "C" void kernel_launch(void* const* d_in, const int* in_sizes, int n_in,
                              void* d_out, int out_size, void* d_ws, size_t ws_size,
                              hipStream_t stream)
{
    const float* x    = (const float*)d_in[0];
    const int*   ei   = (const int*)  d_in[1];
    const float* w1l  = (const float*)d_in[2];
    const float* b1l  = (const float*)d_in[3];
    const float* w1r  = (const float*)d_in[4];
    const float* w2l  = (const float*)d_in[5];
    const float* b2l  = (const float*)d_in[6];
    const float* w2r  = (const float*)d_in[7];
    const float* fc1w = (const float*)d_in[8];
    const float* fc1b = (const float*)d_in[9];
    const float* fc2w = (const float*)d_in[10];
    const float* fc2b = (const float*)d_in[11];
    float* out = (float*)d_out;

    int N = in_sizes[0] / NF;
    int E = in_sizes[1] / 2;
    const int* src = ei;
    const int* dst = ei + E;

    int K = (N + NPB - 1) / NPB;   // 782 buckets

    // ws layout: A16 | B16 | recs[8*K*CAP] | cursor[8*K] | ovf_cnt | ovf
    __half* A16    = (__half*)d_ws;
    __half* B16    = A16 + (size_t)N * HID;
    int*    recs   = (int*)(B16 + (size_t)N * HID);
    int*    cursor = recs + (size_t)NXCD * K * CAP;
    int*    ovfcnt = cursor + (size_t)NXCD * K;
    int2*   ovf    = (int2*)(ovfcnt + 2);

    int ncur = NXCD * K + 1;

    zero_kernel<<<(ncur + 255) / 256, 256, 0, stream>>>(cursor, ncur);
    scatter_bin_kernel<<<(E + 255) / 256, 256, 0, stream>>>(src, dst, cursor, recs,
                                                            ovfcnt, ovf, E, K);

    gemm1_kernel<<<(N + 15) / 16, 256, 0, stream>>>(x, w1l, w1r, A16, B16, N);
    bucket_agg_kernel<<<K, 256, 0, stream>>>(cursor, recs, ovfcnt, ovf,
                                             A16, B16, b1l, B16, N, K);

    gemm2_kernel<<<(N + 15) / 16, 256, 0, stream>>>(B16, w2l, w2r, A16, B16, N);
    bucket_agg_kernel<<<K, 256, 0, stream>>>(cursor, recs, ovfcnt, ovf,
                                             A16, B16, b2l, B16, N, K);

    edge_mlp_kernel<<<(E + 255) / 256, 256, 0, stream>>>(src, dst, B16, fc1w, fc1b,
                                                         fc2w, fc2b, out, E);
}

// Round 7
// 360.458 us; speedup vs baseline: 3.0878x; 1.3899x over previous
//
#include <hip/hip_runtime.h>
#include <hip/hip_fp16.h>
#include <math.h>

#define NF   128
#define HID  16
#define NPB  128          // nodes per bucket (dst >> 7)
#define CAP  768          // records per (xcd, bucket) cell; mean 511
#define NXCD 8
#define SMAX (NXCD * CAP) // max records per bucket in LDS sort (6144)
#define OVF_CAP 262144    // statistically-unreachable overflow list
#define KMAX 1024         // max buckets (N <= 131072)
#define CH   8192         // edges per block in scatter_bin

// ---------------------------------------------------------------------------
__global__ void zero_kernel(int* __restrict__ ptr, int n) {
    int i = blockIdx.x * blockDim.x + threadIdx.x;
    if (i < n) ptr[i] = 0;
}

// ---------------------------------------------------------------------------
// Block-chunked two-pass binning. Each block owns CH consecutive edges:
//   pass 1: LDS histogram by dst bucket
//   reserve: ONE workgroup-scope global atomic per touched bucket -> private
//            contiguous range in this XCD's cell (cursor atomics execute in
//            the XCD's own L2; each cell owned by one XCD — validated R5/R6)
//   pass 2: re-read edges (L2-hot), claim slot via LDS counter, write record
//            into the private range. A line is filled by one block, close in
//            time -> ~single writeback per 64B line (vs 4.8x in R6).
// Record = (dst & 127) << 17 | src   (src < 2^17).
__global__ __launch_bounds__(256) void scatter_bin_kernel(
    const int* __restrict__ src, const int* __restrict__ dst,
    int* __restrict__ cursor, int* __restrict__ recs,
    int* __restrict__ ovf_cnt, int2* __restrict__ ovf, int E, int K)
{
    __shared__ int cnt[KMAX];
    __shared__ int resbase[KMAX];
    __shared__ int cur[KMAX];

    int tid  = threadIdx.x;
    int base = blockIdx.x * CH;

    for (int b = tid; b < K; b += 256) cnt[b] = 0;
    __syncthreads();

    // pass 1: histogram
    for (int i = tid; i < CH; i += 256) {
        int e = base + i;
        if (e < E) atomicAdd(&cnt[((unsigned)dst[e]) >> 7], 1);
    }
    __syncthreads();

    int xcd;
    asm volatile("s_getreg_b32 %0, hwreg(HW_REG_XCC_ID)" : "=s"(xcd));
    xcd &= 7;

    // reserve ranges: one global (XCD-local L2) atomic per touched bucket
    for (int b = tid; b < K; b += 256) {
        int c = cnt[b];
        cur[b] = 0;
        if (c > 0)
            resbase[b] = __hip_atomic_fetch_add(&cursor[xcd * K + b], c,
                                                __ATOMIC_RELAXED,
                                                __HIP_MEMORY_SCOPE_WORKGROUP);
    }
    __syncthreads();

    // pass 2: place records into private ranges
    for (int i = tid; i < CH; i += 256) {
        int e = base + i;
        if (e >= E) continue;
        int s = src[e], d = dst[e];
        int b = ((unsigned)d) >> 7;
        int idx  = atomicAdd(&cur[b], 1);          // LDS
        int slot = resbase[b] + idx;
        if (slot < CAP) {
            recs[((size_t)(xcd * K + b)) * CAP + slot] = ((d & 127) << 17) | s;
        } else {
            int op = atomicAdd(ovf_cnt, 1);        // device scope; ~never
            if (op < OVF_CAP) ovf[op] = make_int2(d, s);
        }
    }
}

// ---------------------------------------------------------------------------
// p16 = x @ wl, q16 = x @ wr
__global__ __launch_bounds__(256) void gemm1_kernel(
    const float* __restrict__ x, const float* __restrict__ wl,
    const float* __restrict__ wr, __half* __restrict__ p,
    __half* __restrict__ q, int N)
{
    __shared__ float swl[NF * HID];
    __shared__ float swr[NF * HID];
    __shared__ float xs[16][132];

    int tid  = threadIdx.x;
    int base = blockIdx.x * 16;

    for (int i = tid; i < NF * HID; i += 256) { swl[i] = wl[i]; swr[i] = wr[i]; }
    for (int i = tid; i < 16 * NF; i += 256) {
        int r = i >> 7, c = i & 127;
        int node = base + r;
        xs[r][c] = (node < N) ? x[(size_t)node * NF + c] : 0.f;
    }
    __syncthreads();

    int r = tid >> 4, f = tid & 15;
    int node = base + r;
    if (node >= N) return;

    float accl = 0.f, accr = 0.f;
    #pragma unroll
    for (int k = 0; k < NF; ++k) {
        float xv = xs[r][k];
        accl += xv * swl[k * HID + f];
        accr += xv * swr[k * HID + f];
    }
    p[(size_t)node * HID + f] = __float2half(accl);
    q[(size_t)node * HID + f] = __float2half(accr);
}

// ---------------------------------------------------------------------------
// p16 = h16 @ wl, q16 = h16 @ wr; q may alias h (LDS-staged before writes)
__global__ __launch_bounds__(256) void gemm2_kernel(
    const __half* __restrict__ h, const float* __restrict__ wl,
    const float* __restrict__ wr, __half* __restrict__ p,
    __half* __restrict__ q, int N)
{
    __shared__ float swl[HID * HID];
    __shared__ float swr[HID * HID];
    __shared__ float hs[256];

    int tid  = threadIdx.x;
    int base = blockIdx.x * 16;
    if (tid < HID * HID) { swl[tid] = wl[tid]; swr[tid] = wr[tid]; }
    int gi = base * HID + tid;
    hs[tid] = (gi < N * HID) ? __half2float(h[gi]) : 0.f;
    __syncthreads();

    int r = tid >> 4, f = tid & 15;
    int node = base + r;
    if (node >= N) return;

    float accl = 0.f, accr = 0.f;
    #pragma unroll
    for (int k = 0; k < HID; ++k) {
        float hv = hs[r * HID + k];
        accl += hv * swl[k * HID + f];
        accr += hv * swr[k * HID + f];
    }
    p[(size_t)node * HID + f] = __float2half(accl);
    q[(size_t)node * HID + f] = __float2half(accr);
}

// ---------------------------------------------------------------------------
// One block per bucket (128 nodes). In-LDS counting sort of the bucket's
// records by local dst, then atomic-free register accumulation:
// 2 threads/node x 8 features, one 16B vector load per record.
// h may alias q (each element read only by its writer thread).
__global__ __launch_bounds__(256) void bucket_agg_kernel(
    const int* __restrict__ cursor, const int* __restrict__ recs,
    const int* __restrict__ ovf_cnt, const int2* __restrict__ ovf,
    const __half* __restrict__ p, const __half* __restrict__ q,
    const float* __restrict__ b, __half* __restrict__ h, int N, int K)
{
    __shared__ int sorted[SMAX];     // 24 KB: src ids grouped by local dst
    __shared__ int cnt[NPB];
    __shared__ int off[NPB];
    __shared__ int cur[NPB];
    __shared__ int scan[NPB];
    __shared__ int s_ovf;

    int bkt = blockIdx.x;
    int tid = threadIdx.x;

    if (tid < NPB) cnt[tid] = 0;
    if (tid == 0) { int v = *ovf_cnt; s_ovf = v < OVF_CAP ? v : OVF_CAP; }
    __syncthreads();

    // Phase A: count per local dst (1 LDS atomic / record)
    for (int xcd = 0; xcd < NXCD; ++xcd) {
        int cell = xcd * K + bkt;
        int len = cursor[cell]; if (len > CAP) len = CAP;
        const int* cr = recs + (size_t)cell * CAP;
        for (int r = tid; r < len; r += 256)
            atomicAdd(&cnt[((unsigned)cr[r]) >> 17], 1);
    }
    if (s_ovf > 0) {
        for (int r = tid; r < s_ovf; r += 256) {
            int2 od = ovf[r];
            if ((od.x >> 7) == bkt) atomicAdd(&cnt[od.x & 127], 1);
        }
    }
    __syncthreads();

    // Phase B: exclusive scan of cnt[128]
    if (tid < NPB) scan[tid] = cnt[tid];
    __syncthreads();
    for (int o = 1; o < NPB; o <<= 1) {
        int v = 0;
        if (tid < NPB && tid >= o) v = scan[tid - o];
        __syncthreads();
        if (tid < NPB) scan[tid] += v;
        __syncthreads();
    }
    if (tid < NPB) { int e = scan[tid] - cnt[tid]; off[tid] = e; cur[tid] = e; }
    __syncthreads();

    // Phase C: scatter src into dl-grouped slots (1 LDS atomic + 1 write)
    for (int xcd = 0; xcd < NXCD; ++xcd) {
        int cell = xcd * K + bkt;
        int len = cursor[cell]; if (len > CAP) len = CAP;
        const int* cr = recs + (size_t)cell * CAP;
        for (int r = tid; r < len; r += 256) {
            int rec = cr[r];
            int slot = atomicAdd(&cur[((unsigned)rec) >> 17], 1);
            if (slot < SMAX) sorted[slot] = rec & 0x1FFFF;
        }
    }
    if (s_ovf > 0) {
        for (int r = tid; r < s_ovf; r += 256) {
            int2 od = ovf[r];
            if ((od.x >> 7) == bkt) {
                int slot = atomicAdd(&cur[od.x & 127], 1);
                if (slot < SMAX) sorted[slot] = od.y;
            }
        }
    }
    __syncthreads();

    // Phase D: atomic-free accumulate. thread = (dl, half of features)
    int dl   = tid >> 1;
    int half = tid & 1;
    int node = (bkt << 7) + dl;
    if (node >= N) return;

    int st = off[dl];
    int n  = cnt[dl];
    if (st > SMAX) st = SMAX;
    if (st + n > SMAX) n = SMAX - st;

    float a0 = 0.f, a1 = 0.f, a2 = 0.f, a3 = 0.f,
          a4 = 0.f, a5 = 0.f, a6 = 0.f, a7 = 0.f;
    for (int i = 0; i < n; ++i) {
        int s = sorted[st + i];
        float4 raw = *(const float4*)(p + (size_t)s * HID + half * 8);
        float2 v0 = __half22float2(*(const __half2*)&raw.x);
        float2 v1 = __half22float2(*(const __half2*)&raw.y);
        float2 v2 = __half22float2(*(const __half2*)&raw.z);
        float2 v3 = __half22float2(*(const __half2*)&raw.w);
        a0 += v0.x; a1 += v0.y; a2 += v1.x; a3 += v1.y;
        a4 += v2.x; a5 += v2.y; a6 += v3.x; a7 += v3.y;
    }

    float inv = 1.f / fmaxf((float)cnt[dl], 1.f);
    int fb = half * 8;
    float4 qraw = *(const float4*)(q + (size_t)node * HID + fb);
    float2 q0 = __half22float2(*(const __half2*)&qraw.x);
    float2 q1 = __half22float2(*(const __half2*)&qraw.y);
    float2 q2 = __half22float2(*(const __half2*)&qraw.z);
    float2 q3 = __half22float2(*(const __half2*)&qraw.w);

    __half2 r0 = __floats2half2_rn(fmaxf(a0*inv + b[fb+0] + q0.x, 0.f),
                                   fmaxf(a1*inv + b[fb+1] + q0.y, 0.f));
    __half2 r1 = __floats2half2_rn(fmaxf(a2*inv + b[fb+2] + q1.x, 0.f),
                                   fmaxf(a3*inv + b[fb+3] + q1.y, 0.f));
    __half2 r2 = __floats2half2_rn(fmaxf(a4*inv + b[fb+4] + q2.x, 0.f),
                                   fmaxf(a5*inv + b[fb+5] + q2.y, 0.f));
    __half2 r3 = __floats2half2_rn(fmaxf(a6*inv + b[fb+6] + q3.x, 0.f),
                                   fmaxf(a7*inv + b[fb+7] + q3.y, 0.f));
    float4 res;
    *(__half2*)&res.x = r0; *(__half2*)&res.y = r1;
    *(__half2*)&res.z = r2; *(__half2*)&res.w = r3;
    *(float4*)(h + (size_t)node * HID + fb) = res;
}

// ---------------------------------------------------------------------------
// per-edge: concat(h[src],h[dst]) -> fc1+relu -> fc2 -> log_softmax
__global__ __launch_bounds__(256) void edge_mlp_kernel(
    const int* __restrict__ src, const int* __restrict__ dst,
    const __half* __restrict__ h,
    const float* __restrict__ fc1w, const float* __restrict__ fc1b,
    const float* __restrict__ fc2w, const float* __restrict__ fc2b,
    float* __restrict__ out, int E)
{
    __shared__ float w1[32 * 16];
    __shared__ float b1[16];
    __shared__ float w2[32];
    __shared__ float b2[2];

    int tid = threadIdx.x;
    for (int i = tid; i < 512; i += 256) w1[i] = fc1w[i];
    if (tid < 16) b1[tid] = fc1b[tid];
    if (tid < 32) w2[tid] = fc2w[tid];
    if (tid < 2)  b2[tid] = fc2b[tid];
    __syncthreads();

    int e = blockIdx.x * blockDim.x + tid;
    if (e >= E) return;
    int s = src[e], d = dst[e];

    float feat[32];
    const __half2* hs2 = (const __half2*)(h + (size_t)s * HID);
    const __half2* hd2 = (const __half2*)(h + (size_t)d * HID);
    #pragma unroll
    for (int i = 0; i < 8; ++i) {
        float2 v = __half22float2(hs2[i]);
        feat[2*i+0] = v.x; feat[2*i+1] = v.y;
    }
    #pragma unroll
    for (int i = 0; i < 8; ++i) {
        float2 v = __half22float2(hd2[i]);
        feat[16+2*i+0] = v.x; feat[16+2*i+1] = v.y;
    }

    float z[16];
    #pragma unroll
    for (int j = 0; j < 16; ++j) z[j] = b1[j];
    #pragma unroll
    for (int i = 0; i < 32; ++i) {
        float fv = feat[i];
        #pragma unroll
        for (int j = 0; j < 16; ++j) z[j] += fv * w1[i * 16 + j];
    }

    float o0 = b2[0], o1 = b2[1];
    #pragma unroll
    for (int j = 0; j < 16; ++j) {
        float zj = fmaxf(z[j], 0.f);
        o0 += zj * w2[2 * j + 0];
        o1 += zj * w2[2 * j + 1];
    }

    float m = fmaxf(o0, o1);
    float lse = m + logf(expf(o0 - m) + expf(o1 - m));
    float2 res; res.x = o0 - lse; res.y = o1 - lse;
    ((float2*)out)[e] = res;
}

// ---------------------------------------------------------------------------
extern "C" void kernel_launch(void* const* d_in, const int* in_sizes, int n_in,
                              void* d_out, int out_size, void* d_ws, size_t ws_size,
                              hipStream_t stream)
{
    const float* x    = (const float*)d_in[0];
    const int*   ei   = (const int*)  d_in[1];
    const float* w1l  = (const float*)d_in[2];
    const float* b1l  = (const float*)d_in[3];
    const float* w1r  = (const float*)d_in[4];
    const float* w2l  = (const float*)d_in[5];
    const float* b2l  = (const float*)d_in[6];
    const float* w2r  = (const float*)d_in[7];
    const float* fc1w = (const float*)d_in[8];
    const float* fc1b = (const float*)d_in[9];
    const float* fc2w = (const float*)d_in[10];
    const float* fc2b = (const float*)d_in[11];
    float* out = (float*)d_out;

    int N = in_sizes[0] / NF;
    int E = in_sizes[1] / 2;
    const int* src = ei;
    const int* dst = ei + E;

    int K = (N + NPB - 1) / NPB;   // 782 buckets (<= KMAX)

    // ws layout: A16 | B16 | recs[8*K*CAP] | cursor[8*K] | ovf_cnt | ovf
    __half* A16    = (__half*)d_ws;
    __half* B16    = A16 + (size_t)N * HID;
    int*    recs   = (int*)(B16 + (size_t)N * HID);
    int*    cursor = recs + (size_t)NXCD * K * CAP;
    int*    ovfcnt = cursor + (size_t)NXCD * K;
    int2*   ovf    = (int2*)(ovfcnt + 2);

    int ncur = NXCD * K + 1;

    zero_kernel<<<(ncur + 255) / 256, 256, 0, stream>>>(cursor, ncur);
    scatter_bin_kernel<<<(E + CH - 1) / CH, 256, 0, stream>>>(src, dst, cursor, recs,
                                                              ovfcnt, ovf, E, K);

    gemm1_kernel<<<(N + 15) / 16, 256, 0, stream>>>(x, w1l, w1r, A16, B16, N);
    bucket_agg_kernel<<<K, 256, 0, stream>>>(cursor, recs, ovfcnt, ovf,
                                             A16, B16, b1l, B16, N, K);

    gemm2_kernel<<<(N + 15) / 16, 256, 0, stream>>>(B16, w2l, w2r, A16, B16, N);
    bucket_agg_kernel<<<K, 256, 0, stream>>>(cursor, recs, ovfcnt, ovf,
                                             A16, B16, b2l, B16, N, K);

    edge_mlp_kernel<<<(E + 255) / 256, 256, 0, stream>>>(src, dst, B16, fc1w, fc1b,
                                                         fc2w, fc2b, out, E);
}

// Round 8
// 356.671 us; speedup vs baseline: 3.1206x; 1.0106x over previous
//
#include <hip/hip_runtime.h>
#include <hip/hip_fp16.h>
#include <math.h>

#define NF   128
#define HID  16
#define NPB  128          // nodes per bucket (dst >> 7)
#define CAP  768          // records per (xcd, bucket) cell; mean 511
#define NXCD 8
#define SMAX (NXCD * CAP) // max records per bucket in LDS sort (6144)
#define OVF_CAP 262144    // statistically-unreachable overflow list
#define KMAX 1024         // max buckets (N <= 131072)
#define CH   8192         // edges per block in scatter_bin

typedef _Float16 half8 __attribute__((ext_vector_type(8)));
typedef float    floatx4 __attribute__((ext_vector_type(4)));

// ---------------------------------------------------------------------------
__global__ void zero_kernel(int* __restrict__ ptr, int n) {
    int i = blockIdx.x * blockDim.x + threadIdx.x;
    if (i < n) ptr[i] = 0;
}

// ---------------------------------------------------------------------------
// Block-chunked two-pass binning (see R7 notes): LDS histogram -> one
// XCD-local L2 atomic per touched bucket -> private contiguous range fill.
// Record = (dst & 127) << 17 | src   (src < 2^17).
__global__ __launch_bounds__(256) void scatter_bin_kernel(
    const int* __restrict__ src, const int* __restrict__ dst,
    int* __restrict__ cursor, int* __restrict__ recs,
    int* __restrict__ ovf_cnt, int2* __restrict__ ovf, int E, int K)
{
    __shared__ int cnt[KMAX];
    __shared__ int resbase[KMAX];
    __shared__ int cur[KMAX];

    int tid  = threadIdx.x;
    int base = blockIdx.x * CH;

    for (int b = tid; b < K; b += 256) cnt[b] = 0;
    __syncthreads();

    for (int i = tid; i < CH; i += 256) {
        int e = base + i;
        if (e < E) atomicAdd(&cnt[((unsigned)dst[e]) >> 7], 1);
    }
    __syncthreads();

    int xcd;
    asm volatile("s_getreg_b32 %0, hwreg(HW_REG_XCC_ID)" : "=s"(xcd));
    xcd &= 7;

    for (int b = tid; b < K; b += 256) {
        int c = cnt[b];
        cur[b] = 0;
        if (c > 0)
            resbase[b] = __hip_atomic_fetch_add(&cursor[xcd * K + b], c,
                                                __ATOMIC_RELAXED,
                                                __HIP_MEMORY_SCOPE_WORKGROUP);
    }
    __syncthreads();

    for (int i = tid; i < CH; i += 256) {
        int e = base + i;
        if (e >= E) continue;
        int s = src[e], d = dst[e];
        int b = ((unsigned)d) >> 7;
        int idx  = atomicAdd(&cur[b], 1);          // LDS
        int slot = resbase[b] + idx;
        if (slot < CAP) {
            recs[((size_t)(xcd * K + b)) * CAP + slot] = ((d & 127) << 17) | s;
        } else {
            int op = atomicAdd(ovf_cnt, 1);        // device scope; ~never
            if (op < OVF_CAP) ovf[op] = make_int2(d, s);
        }
    }
}

// ---------------------------------------------------------------------------
// p16 = x @ wl, q16 = x @ wr
__global__ __launch_bounds__(256) void gemm1_kernel(
    const float* __restrict__ x, const float* __restrict__ wl,
    const float* __restrict__ wr, __half* __restrict__ p,
    __half* __restrict__ q, int N)
{
    __shared__ float swl[NF * HID];
    __shared__ float swr[NF * HID];
    __shared__ float xs[16][132];

    int tid  = threadIdx.x;
    int base = blockIdx.x * 16;

    for (int i = tid; i < NF * HID; i += 256) { swl[i] = wl[i]; swr[i] = wr[i]; }
    for (int i = tid; i < 16 * NF; i += 256) {
        int r = i >> 7, c = i & 127;
        int node = base + r;
        xs[r][c] = (node < N) ? x[(size_t)node * NF + c] : 0.f;
    }
    __syncthreads();

    int r = tid >> 4, f = tid & 15;
    int node = base + r;
    if (node >= N) return;

    float accl = 0.f, accr = 0.f;
    #pragma unroll
    for (int k = 0; k < NF; ++k) {
        float xv = xs[r][k];
        accl += xv * swl[k * HID + f];
        accr += xv * swr[k * HID + f];
    }
    p[(size_t)node * HID + f] = __float2half(accl);
    q[(size_t)node * HID + f] = __float2half(accr);
}

// ---------------------------------------------------------------------------
// p16 = h16 @ wl, q16 = h16 @ wr; q may alias h (LDS-staged before writes)
__global__ __launch_bounds__(256) void gemm2_kernel(
    const __half* __restrict__ h, const float* __restrict__ wl,
    const float* __restrict__ wr, __half* __restrict__ p,
    __half* __restrict__ q, int N)
{
    __shared__ float swl[HID * HID];
    __shared__ float swr[HID * HID];
    __shared__ float hs[256];

    int tid  = threadIdx.x;
    int base = blockIdx.x * 16;
    if (tid < HID * HID) { swl[tid] = wl[tid]; swr[tid] = wr[tid]; }
    int gi = base * HID + tid;
    hs[tid] = (gi < N * HID) ? __half2float(h[gi]) : 0.f;
    __syncthreads();

    int r = tid >> 4, f = tid & 15;
    int node = base + r;
    if (node >= N) return;

    float accl = 0.f, accr = 0.f;
    #pragma unroll
    for (int k = 0; k < HID; ++k) {
        float hv = hs[r * HID + k];
        accl += hv * swl[k * HID + f];
        accr += hv * swr[k * HID + f];
    }
    p[(size_t)node * HID + f] = __float2half(accl);
    q[(size_t)node * HID + f] = __float2half(accr);
}

// ---------------------------------------------------------------------------
// One block per bucket (128 nodes): in-LDS counting sort, then atomic-free
// register accumulation (2 threads/node x 8 features). h may alias q.
__global__ __launch_bounds__(256) void bucket_agg_kernel(
    const int* __restrict__ cursor, const int* __restrict__ recs,
    const int* __restrict__ ovf_cnt, const int2* __restrict__ ovf,
    const __half* __restrict__ p, const __half* __restrict__ q,
    const float* __restrict__ b, __half* __restrict__ h, int N, int K)
{
    __shared__ int sorted[SMAX];
    __shared__ int cnt[NPB];
    __shared__ int off[NPB];
    __shared__ int cur[NPB];
    __shared__ int scan[NPB];
    __shared__ int s_ovf;

    int bkt = blockIdx.x;
    int tid = threadIdx.x;

    if (tid < NPB) cnt[tid] = 0;
    if (tid == 0) { int v = *ovf_cnt; s_ovf = v < OVF_CAP ? v : OVF_CAP; }
    __syncthreads();

    for (int xcd = 0; xcd < NXCD; ++xcd) {
        int cell = xcd * K + bkt;
        int len = cursor[cell]; if (len > CAP) len = CAP;
        const int* cr = recs + (size_t)cell * CAP;
        for (int r = tid; r < len; r += 256)
            atomicAdd(&cnt[((unsigned)cr[r]) >> 17], 1);
    }
    if (s_ovf > 0) {
        for (int r = tid; r < s_ovf; r += 256) {
            int2 od = ovf[r];
            if ((od.x >> 7) == bkt) atomicAdd(&cnt[od.x & 127], 1);
        }
    }
    __syncthreads();

    if (tid < NPB) scan[tid] = cnt[tid];
    __syncthreads();
    for (int o = 1; o < NPB; o <<= 1) {
        int v = 0;
        if (tid < NPB && tid >= o) v = scan[tid - o];
        __syncthreads();
        if (tid < NPB) scan[tid] += v;
        __syncthreads();
    }
    if (tid < NPB) { int e = scan[tid] - cnt[tid]; off[tid] = e; cur[tid] = e; }
    __syncthreads();

    for (int xcd = 0; xcd < NXCD; ++xcd) {
        int cell = xcd * K + bkt;
        int len = cursor[cell]; if (len > CAP) len = CAP;
        const int* cr = recs + (size_t)cell * CAP;
        for (int r = tid; r < len; r += 256) {
            int rec = cr[r];
            int slot = atomicAdd(&cur[((unsigned)rec) >> 17], 1);
            if (slot < SMAX) sorted[slot] = rec & 0x1FFFF;
        }
    }
    if (s_ovf > 0) {
        for (int r = tid; r < s_ovf; r += 256) {
            int2 od = ovf[r];
            if ((od.x >> 7) == bkt) {
                int slot = atomicAdd(&cur[od.x & 127], 1);
                if (slot < SMAX) sorted[slot] = od.y;
            }
        }
    }
    __syncthreads();

    int dl   = tid >> 1;
    int half = tid & 1;
    int node = (bkt << 7) + dl;
    if (node >= N) return;

    int st = off[dl];
    int n  = cnt[dl];
    if (st > SMAX) st = SMAX;
    if (st + n > SMAX) n = SMAX - st;

    float a0 = 0.f, a1 = 0.f, a2 = 0.f, a3 = 0.f,
          a4 = 0.f, a5 = 0.f, a6 = 0.f, a7 = 0.f;
    for (int i = 0; i < n; ++i) {
        int s = sorted[st + i];
        float4 raw = *(const float4*)(p + (size_t)s * HID + half * 8);
        float2 v0 = __half22float2(*(const __half2*)&raw.x);
        float2 v1 = __half22float2(*(const __half2*)&raw.y);
        float2 v2 = __half22float2(*(const __half2*)&raw.z);
        float2 v3 = __half22float2(*(const __half2*)&raw.w);
        a0 += v0.x; a1 += v0.y; a2 += v1.x; a3 += v1.y;
        a4 += v2.x; a5 += v2.y; a6 += v3.x; a7 += v3.y;
    }

    float inv = 1.f / fmaxf((float)cnt[dl], 1.f);
    int fb = half * 8;
    float4 qraw = *(const float4*)(q + (size_t)node * HID + fb);
    float2 q0 = __half22float2(*(const __half2*)&qraw.x);
    float2 q1 = __half22float2(*(const __half2*)&qraw.y);
    float2 q2 = __half22float2(*(const __half2*)&qraw.z);
    float2 q3 = __half22float2(*(const __half2*)&qraw.w);

    __half2 r0 = __floats2half2_rn(fmaxf(a0*inv + b[fb+0] + q0.x, 0.f),
                                   fmaxf(a1*inv + b[fb+1] + q0.y, 0.f));
    __half2 r1 = __floats2half2_rn(fmaxf(a2*inv + b[fb+2] + q1.x, 0.f),
                                   fmaxf(a3*inv + b[fb+3] + q1.y, 0.f));
    __half2 r2 = __floats2half2_rn(fmaxf(a4*inv + b[fb+4] + q2.x, 0.f),
                                   fmaxf(a5*inv + b[fb+5] + q2.y, 0.f));
    __half2 r3 = __floats2half2_rn(fmaxf(a6*inv + b[fb+6] + q3.x, 0.f),
                                   fmaxf(a7*inv + b[fb+7] + q3.y, 0.f));
    float4 res;
    *(__half2*)&res.x = r0; *(__half2*)&res.y = r1;
    *(__half2*)&res.z = r2; *(__half2*)&res.w = r3;
    *(float4*)(h + (size_t)node * HID + fb) = res;
}

// ---------------------------------------------------------------------------
// MFMA edge MLP. One wave = tile of 16 edges per iteration.
// A[m=lane&15][k=quad*8+j]: quad 0/1 = h[src] halves, quad 2/3 = h[dst]
// halves -> one 16B load per lane. B = fc1w fp16 in registers.
// C: col=lane&15 (out feature n), row=quad*4+reg (edge m).
// bias+relu+fc2 partials in-register, butterfly shfl_xor(1,2,4,8) reduces
// over the 16 features, lane n==reg stores log_softmax'd float2.
__global__ __launch_bounds__(256) void edge_mlp_mfma_kernel(
    const int* __restrict__ src, const int* __restrict__ dst,
    const __half* __restrict__ h,
    const float* __restrict__ fc1w, const float* __restrict__ fc1b,
    const float* __restrict__ fc2w, const float* __restrict__ fc2b,
    float* __restrict__ out, int E, int ntiles)
{
    int lane   = threadIdx.x & 63;
    int wave   = (blockIdx.x * blockDim.x + threadIdx.x) >> 6;
    int nwaves = (gridDim.x * blockDim.x) >> 6;

    int n = lane & 15;      // out feature (B col, C col); also A row for loads
    int q = lane >> 4;      // quad

    half8 bfrag;
    #pragma unroll
    for (int j = 0; j < 8; ++j)
        bfrag[j] = (_Float16)fc1w[(q * 8 + j) * 16 + n];

    float bias1 = fc1b[n];
    float w2c0  = fc2w[n * 2 + 0];
    float w2c1  = fc2w[n * 2 + 1];
    float bb0 = fc2b[0], bb1 = fc2b[1];

    for (int t = wave; t < ntiles; t += nwaves) {
        int e   = t * 16 + n;
        int e_c = e < E ? e : E - 1;
        int idx = (q < 2) ? src[e_c] : dst[e_c];
        half8 afrag = *(const half8*)(h + (size_t)idx * HID + (q & 1) * 8);

        floatx4 acc = {0.f, 0.f, 0.f, 0.f};
        acc = __builtin_amdgcn_mfma_f32_16x16x32_f16(afrag, bfrag, acc, 0, 0, 0);

        float o0[4], o1[4];
        #pragma unroll
        for (int r = 0; r < 4; ++r) {
            float z = fmaxf(acc[r] + bias1, 0.f);
            o0[r] = z * w2c0;
            o1[r] = z * w2c1;
        }
        #pragma unroll
        for (int s = 1; s < 16; s <<= 1) {
            #pragma unroll
            for (int r = 0; r < 4; ++r) {
                o0[r] += __shfl_xor(o0[r], s);
                o1[r] += __shfl_xor(o1[r], s);
            }
        }
        #pragma unroll
        for (int r = 0; r < 4; ++r) {
            if (n == r) {
                int eo = t * 16 + q * 4 + r;
                if (eo < E) {
                    float a  = o0[r] + bb0;
                    float c  = o1[r] + bb1;
                    float mx = fmaxf(a, c);
                    float lse = mx + __logf(__expf(a - mx) + __expf(c - mx));
                    ((float2*)out)[eo] = make_float2(a - lse, c - lse);
                }
            }
        }
    }
}

// ---------------------------------------------------------------------------
extern "C" void kernel_launch(void* const* d_in, const int* in_sizes, int n_in,
                              void* d_out, int out_size, void* d_ws, size_t ws_size,
                              hipStream_t stream)
{
    const float* x    = (const float*)d_in[0];
    const int*   ei   = (const int*)  d_in[1];
    const float* w1l  = (const float*)d_in[2];
    const float* b1l  = (const float*)d_in[3];
    const float* w1r  = (const float*)d_in[4];
    const float* w2l  = (const float*)d_in[5];
    const float* b2l  = (const float*)d_in[6];
    const float* w2r  = (const float*)d_in[7];
    const float* fc1w = (const float*)d_in[8];
    const float* fc1b = (const float*)d_in[9];
    const float* fc2w = (const float*)d_in[10];
    const float* fc2b = (const float*)d_in[11];
    float* out = (float*)d_out;

    int N = in_sizes[0] / NF;
    int E = in_sizes[1] / 2;
    const int* src = ei;
    const int* dst = ei + E;

    int K = (N + NPB - 1) / NPB;   // 782 buckets (<= KMAX)

    // ws layout: A16 | B16 | recs[8*K*CAP] | cursor[8*K] | ovf_cnt | ovf
    __half* A16    = (__half*)d_ws;
    __half* B16    = A16 + (size_t)N * HID;
    int*    recs   = (int*)(B16 + (size_t)N * HID);
    int*    cursor = recs + (size_t)NXCD * K * CAP;
    int*    ovfcnt = cursor + (size_t)NXCD * K;
    int2*   ovf    = (int2*)(ovfcnt + 2);

    int ncur = NXCD * K + 1;

    zero_kernel<<<(ncur + 255) / 256, 256, 0, stream>>>(cursor, ncur);
    scatter_bin_kernel<<<(E + CH - 1) / CH, 256, 0, stream>>>(src, dst, cursor, recs,
                                                              ovfcnt, ovf, E, K);

    gemm1_kernel<<<(N + 15) / 16, 256, 0, stream>>>(x, w1l, w1r, A16, B16, N);
    bucket_agg_kernel<<<K, 256, 0, stream>>>(cursor, recs, ovfcnt, ovf,
                                             A16, B16, b1l, B16, N, K);

    gemm2_kernel<<<(N + 15) / 16, 256, 0, stream>>>(B16, w2l, w2r, A16, B16, N);
    bucket_agg_kernel<<<K, 256, 0, stream>>>(cursor, recs, ovfcnt, ovf,
                                             A16, B16, b2l, B16, N, K);

    int ntiles = (E + 15) / 16;
    edge_mlp_mfma_kernel<<<1024, 256, 0, stream>>>(src, dst, B16, fc1w, fc1b,
                                                   fc2w, fc2b, out, E, ntiles);
}